// Round 15
// baseline (46.451 us; speedup 1.0000x reference)
//
#include <hip/hip_runtime.h>
#include <math.h>

// out[b,o] = min_i(W[o,i]+X[b,i]) + max_i(W[o,i]+X[b,i])
// B=1024, OUT=1024, IN=512, fp32.
//
// R15: shrink the DS+VALU sum (R4-R14: wall == DS + VALU, scheduling can't
// overlap them on this part -- three independent attempts all null).
//  - 8x8 per-lane micro over a 64x64 tile -> DS reads 15.4 -> 10.2 us.
//  - k-paired quads + f2 adds (v_pk_add_f32) -> VALU 13.7 -> 10.2 us.
//  - keep the proven fudge-0 dispatch shape: 256-thr/4-wave blocks, 512
//    blocks = 2/CU, via K-split across blockIdx.z (two 256-k halves);
//    partial mn/mx -> d_ws (16 MB), tiny combine kernel finishes.
//  - LDS layout: quad (q,im) at byte kp*512 + q*128 + im*16 (rows im*8+2q,
//    +1 as (k0,k1) pairs) -> b128 read banks im*4: conflict-free.
//  - wave-private dbuf (8 KB/wave), zero main-loop barriers, 2-round merge
//    tree (state 128 floats/lane, 32 KB slots, 64 KB LDS total).

typedef float f4 __attribute__((ext_vector_type(4)));
typedef float f2 __attribute__((ext_vector_type(2)));

constexpr int B_DIM  = 1024;
constexpr int O_DIM  = 1024;
constexpr int IN_DIM = 512;
constexpr int TILE   = 64;
constexpr int P      = B_DIM * O_DIM;   // 1M outputs

// KSPLIT=2: two k-halves across blockIdx.z, partials to ws.
// KSPLIT=1: full K per block, write out directly (fallback, grid 256).
template <int KSPLIT>
__global__ __launch_bounds__(256) void tropical_gemm(
    const float* __restrict__ X, const float* __restrict__ W,
    float* __restrict__ out, float* __restrict__ ws) {
    constexpr int KW     = (KSPLIT == 2) ? 64 : 128;  // k per wave
    constexpr int NSTAGE = KW / 8;
    __shared__ float lds[16384];   // 64 KB: loop 4x2048 fl; merge 2x8192 fl

    const int tid  = threadIdx.x;
    const int w    = tid >> 6;
    const int lane = tid & 63;
    const int im   = lane >> 3;    // row-block 0..7
    const int in_  = lane & 7;     // col-block 0..7
    const int b0   = blockIdx.y * TILE;
    const int o0   = blockIdx.x * TILE;
    const int kh   = (KSPLIT == 2) ? blockIdx.z : 0;
    const int kbase = kh * (IN_DIM / KSPLIT) + w * KW;

    const float* Xp = X + (size_t)(b0 + lane) * IN_DIM + kbase;
    const float* Wp = W + (size_t)(o0 + lane) * IN_DIM + kbase;

    float* wbase = &lds[w * 2048];   // wave-private 8 KB (2 buf x 1024 fl)
    // staging f2 slot for row/col r=lane (float offset within buffer):
    const int stw = ((lane & 7) >> 1) * 32 + (lane >> 3) * 4 + (lane & 1) * 2;

    float mn[8][8], mx[8][8];
#pragma unroll
    for (int i = 0; i < 8; ++i)
#pragma unroll
        for (int j = 0; j < 8; ++j) { mn[i][j] = INFINITY; mx[i][j] = -INFINITY; }

#define PF(S)                                                                 \
    do {                                                                      \
        xa = *(const f4*)(Xp + (S) * 8);                                      \
        xb = *(const f4*)(Xp + (S) * 8 + 4);                                  \
        wa = *(const f4*)(Wp + (S) * 8);                                      \
        wb = *(const f4*)(Wp + (S) * 8 + 4);                                  \
    } while (0)

#define STAGE(BUF)                                                            \
    do {                                                                      \
        float* dX_ = wbase + (BUF) * 1024;                                    \
        float* dW_ = dX_ + 512;                                               \
        f2 x0_ = {xa[0], xa[1]}, x1_ = {xa[2], xa[3]};                        \
        f2 x2_ = {xb[0], xb[1]}, x3_ = {xb[2], xb[3]};                        \
        f2 w0_ = {wa[0], wa[1]}, w1_ = {wa[2], wa[3]};                        \
        f2 w2_ = {wb[0], wb[1]}, w3_ = {wb[2], wb[3]};                        \
        *(f2*)(dX_ + 0 * 128 + stw) = x0_;                                    \
        *(f2*)(dX_ + 1 * 128 + stw) = x1_;                                    \
        *(f2*)(dX_ + 2 * 128 + stw) = x2_;                                    \
        *(f2*)(dX_ + 3 * 128 + stw) = x3_;                                    \
        *(f2*)(dW_ + 0 * 128 + stw) = w0_;                                    \
        *(f2*)(dW_ + 1 * 128 + stw) = w1_;                                    \
        *(f2*)(dW_ + 2 * 128 + stw) = w2_;                                    \
        *(f2*)(dW_ + 3 * 128 + stw) = w3_;                                    \
    } while (0)

    // one k-pair: 8 b128 reads, 64x (pk_add + min3 + max3) for 128 triples
#define KPBODY(KP, SX, SW)                                                    \
    do {                                                                      \
        f4 xq[4], wq[4];                                                      \
        _Pragma("unroll")                                                     \
        for (int q_ = 0; q_ < 4; ++q_)                                        \
            xq[q_] = *(const f4*)((SX) + (KP) * 128 + q_ * 32 + im * 4);      \
        _Pragma("unroll")                                                     \
        for (int q_ = 0; q_ < 4; ++q_)                                        \
            wq[q_] = *(const f4*)((SW) + (KP) * 128 + q_ * 32 + in_ * 4);     \
        _Pragma("unroll")                                                     \
        for (int q_ = 0; q_ < 4; ++q_) {                                      \
            f2 xl_ = {xq[q_][0], xq[q_][1]};                                  \
            f2 xh_ = {xq[q_][2], xq[q_][3]};                                  \
            _Pragma("unroll")                                                 \
            for (int p_ = 0; p_ < 4; ++p_) {                                  \
                f2 wl_  = {wq[p_][0], wq[p_][1]};                             \
                f2 wh_  = {wq[p_][2], wq[p_][3]};                             \
                f2 s00_ = xl_ + wl_;                                          \
                f2 s01_ = xl_ + wh_;                                          \
                f2 s10_ = xh_ + wl_;                                          \
                f2 s11_ = xh_ + wh_;                                          \
                asm("v_min3_f32 %0, %1, %2, %0"                               \
                    : "+v"(mn[2 * q_][2 * p_]) : "v"(s00_[0]), "v"(s00_[1])); \
                asm("v_max3_f32 %0, %1, %2, %0"                               \
                    : "+v"(mx[2 * q_][2 * p_]) : "v"(s00_[0]), "v"(s00_[1])); \
                asm("v_min3_f32 %0, %1, %2, %0"                               \
                    : "+v"(mn[2 * q_][2 * p_ + 1]) : "v"(s01_[0]), "v"(s01_[1])); \
                asm("v_max3_f32 %0, %1, %2, %0"                               \
                    : "+v"(mx[2 * q_][2 * p_ + 1]) : "v"(s01_[0]), "v"(s01_[1])); \
                asm("v_min3_f32 %0, %1, %2, %0"                               \
                    : "+v"(mn[2 * q_ + 1][2 * p_]) : "v"(s10_[0]), "v"(s10_[1])); \
                asm("v_max3_f32 %0, %1, %2, %0"                               \
                    : "+v"(mx[2 * q_ + 1][2 * p_]) : "v"(s10_[0]), "v"(s10_[1])); \
                asm("v_min3_f32 %0, %1, %2, %0"                               \
                    : "+v"(mn[2 * q_ + 1][2 * p_ + 1]) : "v"(s11_[0]), "v"(s11_[1])); \
                asm("v_max3_f32 %0, %1, %2, %0"                               \
                    : "+v"(mx[2 * q_ + 1][2 * p_ + 1]) : "v"(s11_[0]), "v"(s11_[1])); \
            }                                                                 \
        }                                                                     \
    } while (0)

    // ---- main loop (wave-private, no barriers) ----
    f4 xa, xb, wa, wb;
    PF(0);
    STAGE(0);
    PF(1);

#pragma unroll 1
    for (int s = 0; s < NSTAGE; ++s) {
        const float* sX = wbase + (s & 1) * 1024;
        const float* sW = sX + 512;
        KPBODY(0, sX, sW);
        KPBODY(1, sX, sW);
        if (s + 1 < NSTAGE) {
            STAGE((s + 1) & 1);         // from globals prefetched last iter
            if (s + 2 < NSTAGE) PF(s + 2);
        }
        KPBODY(2, sX, sW);
        KPBODY(3, sX, sW);
    }
#undef PF
#undef STAGE
#undef KPBODY

    // ---- merge 4 wave partials: 2-round tree, 32 KB slots ----
#define DUMP_STATE(SL)                                                        \
    do {                                                                      \
        float* p_ = lds + (SL) * 8192 + lane * 4;                             \
        _Pragma("unroll")                                                     \
        for (int r_ = 0; r_ < 8; ++r_) {                                      \
            f4 a_ = {mn[r_][0], mn[r_][1], mn[r_][2], mn[r_][3]};             \
            f4 b_ = {mn[r_][4], mn[r_][5], mn[r_][6], mn[r_][7]};             \
            f4 c_ = {mx[r_][0], mx[r_][1], mx[r_][2], mx[r_][3]};             \
            f4 d_ = {mx[r_][4], mx[r_][5], mx[r_][6], mx[r_][7]};             \
            *(f4*)(p_ + (2 * r_) * 256)      = a_;                            \
            *(f4*)(p_ + (2 * r_ + 1) * 256)  = b_;                            \
            *(f4*)(p_ + (16 + 2 * r_) * 256) = c_;                            \
            *(f4*)(p_ + (17 + 2 * r_) * 256) = d_;                            \
        }                                                                     \
    } while (0)

#define MERGE_STATE(SL)                                                       \
    do {                                                                      \
        const float* p_ = lds + (SL) * 8192 + lane * 4;                       \
        _Pragma("unroll")                                                     \
        for (int r_ = 0; r_ < 8; ++r_) {                                      \
            f4 a_ = *(const f4*)(p_ + (2 * r_) * 256);                        \
            f4 b_ = *(const f4*)(p_ + (2 * r_ + 1) * 256);                    \
            f4 c_ = *(const f4*)(p_ + (16 + 2 * r_) * 256);                   \
            f4 d_ = *(const f4*)(p_ + (17 + 2 * r_) * 256);                   \
            _Pragma("unroll")                                                 \
            for (int j_ = 0; j_ < 4; ++j_) {                                  \
                mn[r_][j_]     = fminf(mn[r_][j_],     a_[j_]);               \
                mn[r_][4 + j_] = fminf(mn[r_][4 + j_], b_[j_]);               \
                mx[r_][j_]     = fmaxf(mx[r_][j_],     c_[j_]);               \
                mx[r_][4 + j_] = fmaxf(mx[r_][4 + j_], d_[j_]);               \
            }                                                                 \
        }                                                                     \
    } while (0)

    __syncthreads();
    if (w == 2) DUMP_STATE(0);
    if (w == 3) DUMP_STATE(1);
    __syncthreads();
    if (w == 0) MERGE_STATE(0);
    if (w == 1) MERGE_STATE(1);
    __syncthreads();
    if (w == 1) DUMP_STATE(0);
    __syncthreads();
    if (w == 0) {
        MERGE_STATE(0);
        if (KSPLIT == 2) {
            float* mnp = ws + (size_t)kh * 2 * P;
            float* mxp = mnp + P;
#pragma unroll
            for (int r = 0; r < 8; ++r) {
                const size_t off = (size_t)(b0 + im * 8 + r) * O_DIM + o0 + in_ * 8;
                f4 a = {mn[r][0], mn[r][1], mn[r][2], mn[r][3]};
                f4 b = {mn[r][4], mn[r][5], mn[r][6], mn[r][7]};
                f4 c = {mx[r][0], mx[r][1], mx[r][2], mx[r][3]};
                f4 d = {mx[r][4], mx[r][5], mx[r][6], mx[r][7]};
                *(f4*)(mnp + off)     = a;
                *(f4*)(mnp + off + 4) = b;
                *(f4*)(mxp + off)     = c;
                *(f4*)(mxp + off + 4) = d;
            }
        } else {
            float* op = out + (size_t)(b0 + im * 8) * O_DIM + o0 + in_ * 8;
#pragma unroll
            for (int r = 0; r < 8; ++r) {
                f4 v0 = {mn[r][0] + mx[r][0], mn[r][1] + mx[r][1],
                         mn[r][2] + mx[r][2], mn[r][3] + mx[r][3]};
                f4 v1 = {mn[r][4] + mx[r][4], mn[r][5] + mx[r][5],
                         mn[r][6] + mx[r][6], mn[r][7] + mx[r][7]};
                *(f4*)(op + (size_t)r * O_DIM)     = v0;
                *(f4*)(op + (size_t)r * O_DIM + 4) = v1;
            }
        }
    }
#undef DUMP_STATE
#undef MERGE_STATE
}

// out = min(mn0, mn1) + max(mx0, mx1); 1 f4 per thread, grid 1024x256.
__global__ __launch_bounds__(256) void combine_k(
    const float* __restrict__ ws, float* __restrict__ out) {
    const int i = (blockIdx.x * 256 + threadIdx.x) * 4;
    f4 a = *(const f4*)(ws + i);              // mn kh0
    f4 b = *(const f4*)(ws + 2 * P + i);      // mn kh1
    f4 c = *(const f4*)(ws + P + i);          // mx kh0
    f4 d = *(const f4*)(ws + 3 * P + i);      // mx kh1
    f4 r;
#pragma unroll
    for (int j = 0; j < 4; ++j) r[j] = fminf(a[j], b[j]) + fmaxf(c[j], d[j]);
    *(f4*)(out + i) = r;
}

extern "C" void kernel_launch(void* const* d_in, const int* in_sizes, int n_in,
                              void* d_out, int out_size, void* d_ws, size_t ws_size,
                              hipStream_t stream) {
    (void)in_sizes; (void)n_in; (void)out_size;
    const float* X = (const float*)d_in[0];
    const float* W = (const float*)d_in[1];
    float* out     = (float*)d_out;

    const size_t need = (size_t)4 * P * sizeof(float);   // 16 MB partials
    if (ws_size >= need) {
        tropical_gemm<2><<<dim3(16, 16, 2), dim3(256), 0, stream>>>(
            X, W, out, (float*)d_ws);
        combine_k<<<dim3(1024), dim3(256), 0, stream>>>((const float*)d_ws, out);
    } else {
        tropical_gemm<1><<<dim3(16, 16, 1), dim3(256), 0, stream>>>(
            X, W, out, nullptr);
    }
}